// Round 1
// baseline (245.054 us; speedup 1.0000x reference)
//
#include <hip/hip_runtime.h>
#include <cmath>

#define BB 4
#define NN 2048
#define DIN 128
#define HH 4
#define HD 32
#define KSEL 204            // int(0.1 * 2048)
#define BH (BB*HH)

// ---------------------------------------------------------------------------
// K1: Wh[bh][n][d] = sum_f h[b][n][f] * W[h][f][d]
__global__ void wh_kernel(const float* __restrict__ h, const float* __restrict__ W,
                          float* __restrict__ Wh) {
    int t = blockIdx.x * blockDim.x + threadIdx.x;   // 0 .. BH*NN*HD-1
    int d  = t & (HD - 1);
    int n  = (t >> 5) & (NN - 1);
    int bh = t >> 16;
    int b = bh >> 2, hh = bh & 3;
    const float* hrow = h + (size_t)(b * NN + n) * DIN;
    const float* wcol = W + (size_t)hh * DIN * HD + d;
    float acc = 0.f;
#pragma unroll 8
    for (int f = 0; f < DIN; ++f)
        acc += hrow[f] * wcol[f * HD];
    Wh[t] = acc;
}

// ---------------------------------------------------------------------------
// K2: s_i[bh][n] = Wh[bh][n][:] . a[h][:32] ;  s_j with a[h][32:]
__global__ void s_kernel(const float* __restrict__ Wh, const float* __restrict__ a,
                         float* __restrict__ si, float* __restrict__ sj) {
    int t = blockIdx.x * blockDim.x + threadIdx.x;   // 0..BH*NN-1
    int bh = t >> 11;
    int hh = bh & 3;
    const float* wr = Wh + (size_t)t * HD;
    const float* a1 = a + hh * 2 * HD;
    const float* a2 = a1 + HD;
    float s1 = 0.f, s2 = 0.f;
#pragma unroll
    for (int d = 0; d < HD; ++d) {
        float w = wr[d];
        s1 += w * a1[d];
        s2 += w * a2[d];
    }
    si[t] = s1;
    sj[t] = s2;
}

// ---------------------------------------------------------------------------
// K3: rank[bh][j] = #{ j' : s[j'] > s[j]  or (s[j']==s[j] and j' < j) }
// grid = BH*8 blocks, 256 threads; each block handles 256 j's of one (b,h)
__global__ void rank_kernel(const float* __restrict__ sj, int* __restrict__ rank) {
    int bh    = blockIdx.x >> 3;
    int chunk = blockIdx.x & 7;
    __shared__ float sv[NN];
    const float* s = sj + (size_t)bh * NN;
    for (int j = threadIdx.x; j < NN; j += 256) sv[j] = s[j];
    __syncthreads();
    int j0 = chunk * 256 + threadIdx.x;
    float v = sv[j0];
    int r = 0;
#pragma unroll 4
    for (int jp = 0; jp < NN; ++jp) {
        float x = sv[jp];
        r += (x > v) ? 1 : ((x == v && jp < j0) ? 1 : 0);
    }
    rank[bh * NN + j0] = r;
}

// ---------------------------------------------------------------------------
// K4: compact selected (rank < KSEL) indices ascending; also s_j values + max
__global__ void compact_kernel(const float* __restrict__ sj, const int* __restrict__ rank,
                               int* __restrict__ idxsel, float* __restrict__ sjsel,
                               float* __restrict__ sjmax) {
    int bh = blockIdx.x;
    __shared__ int   psum[256];
    __shared__ float mx[256];
    int t = threadIdx.x;
    const int base = bh * NN;
    int flags[8];
    int cnt = 0;
    float lmax = -1e30f;
    int j0 = t * 8;
#pragma unroll
    for (int r = 0; r < 8; ++r) {
        int j = j0 + r;
        int f = (rank[base + j] < KSEL) ? 1 : 0;
        flags[r] = f;
        cnt += f;
        lmax = fmaxf(lmax, sj[base + j]);
    }
    psum[t] = cnt;
    mx[t] = lmax;
    __syncthreads();
    if (t == 0) {
        int run = 0;
        float m = -1e30f;
        for (int i = 0; i < 256; ++i) {
            int c = psum[i];
            psum[i] = run;
            run += c;
            m = fmaxf(m, mx[i]);
        }
        sjmax[bh] = m;
    }
    __syncthreads();
    int pos = psum[t];
#pragma unroll
    for (int r = 0; r < 8; ++r) {
        if (flags[r]) {
            int j = j0 + r;
            idxsel[bh * KSEL + pos] = j;
            sjsel[bh * KSEL + pos]  = sj[base + j];
            pos++;
        }
    }
}

// ---------------------------------------------------------------------------
// K5: main. One block = (b,h, 32 rows); wave w handles 8 rows sequentially.
// out[b][i][h*32+d] = (1/Z_i) * sum_{j in S} exp(lrelu(s_i+s_j)-m_i)*adj[b][i][idx_j]*Wh[j][d]
__global__ __launch_bounds__(256) void attn_kernel(
        const float* __restrict__ adj, const float* __restrict__ Wh,
        const float* __restrict__ si, const int* __restrict__ idxsel,
        const float* __restrict__ sjsel, const float* __restrict__ sjmax,
        float* __restrict__ out) {
    int bh   = blockIdx.x >> 6;
    int tile = blockIdx.x & 63;
    int b = bh >> 2, hh = bh & 3;
    __shared__ int   idxS[KSEL];
    __shared__ float sjS[KSEL];
    __shared__ float WhS[KSEL][HD];
    __shared__ float coef[4][KSEL];
    int t = threadIdx.x;
    for (int j = t; j < KSEL; j += 256) {
        idxS[j] = idxsel[bh * KSEL + j];
        sjS[j]  = sjsel[bh * KSEL + j];
    }
    __syncthreads();
    for (int e = t; e < KSEL * HD; e += 256) {
        int j = e >> 5, d = e & 31;
        WhS[j][d] = Wh[((size_t)bh * NN + idxS[j]) * HD + d];
    }
    float smax = sjmax[bh];
    __syncthreads();
    int w = t >> 6, lane = t & 63;
    const float* adjb = adj + (size_t)b * NN * NN;
    for (int rr = 0; rr < 8; ++rr) {
        int i = tile * 32 + w * 8 + rr;
        float siv = si[bh * NN + i];
        float m = siv + smax;
        m = (m >= 0.f) ? m : 0.2f * m;
        const float* adjrow = adjb + (size_t)i * NN;
        float z = 0.f;
        for (int jj = lane; jj < KSEL; jj += 64) {
            float e = siv + sjS[jj];
            e = (e >= 0.f) ? e : 0.2f * e;
            float c = __expf(e - m);
            coef[w][jj] = c * adjrow[idxS[jj]];
            z += c;
        }
#pragma unroll
        for (int off = 32; off >= 1; off >>= 1) z += __shfl_xor(z, off);
        float invZ = 1.f / z;
        int d = lane & 31, g = lane >> 5;
        float acc = 0.f;
        for (int jj = g; jj < KSEL; jj += 2)
            acc += coef[w][jj] * WhS[jj][d];
        acc += __shfl_xor(acc, 32);
        if (g == 0)
            out[((size_t)(b * NN + i)) * (HH * HD) + hh * HD + d] = acc * invZ;
    }
}

// ---------------------------------------------------------------------------
extern "C" void kernel_launch(void* const* d_in, const int* in_sizes, int n_in,
                              void* d_out, int out_size, void* d_ws, size_t ws_size,
                              hipStream_t stream) {
    const float* h   = (const float*)d_in[0];   // [B,N,DIN]
    const float* adj = (const float*)d_in[1];   // [B,N,N]
    const float* W   = (const float*)d_in[2];   // [H,DIN,HD]
    const float* a   = (const float*)d_in[3];   // [H,2*HD]
    float* out = (float*)d_out;                 // [B,N,H*HD]

    float* Wh     = (float*)d_ws;               // BH*NN*HD
    float* si     = Wh + (size_t)BH * NN * HD;  // BH*NN
    float* sj     = si + (size_t)BH * NN;       // BH*NN
    int*   rank   = (int*)(sj + (size_t)BH * NN);     // BH*NN
    int*   idxsel = rank + (size_t)BH * NN;           // BH*KSEL
    float* sjsel  = (float*)(idxsel + (size_t)BH * KSEL); // BH*KSEL
    float* sjmax  = sjsel + (size_t)BH * KSEL;        // BH

    wh_kernel<<<(BH * NN * HD) / 256, 256, 0, stream>>>(h, W, Wh);
    s_kernel<<<(BH * NN) / 256, 256, 0, stream>>>(Wh, a, si, sj);
    rank_kernel<<<BH * 8, 256, 0, stream>>>(sj, rank);
    compact_kernel<<<BH, 256, 0, stream>>>(sj, rank, idxsel, sjsel, sjmax);
    attn_kernel<<<BH * 64, 256, 0, stream>>>(adj, Wh, si, idxsel, sjsel, sjmax, out);
}

// Round 2
// 177.012 us; speedup vs baseline: 1.3844x; 1.3844x over previous
//
#include <hip/hip_runtime.h>
#include <hip/hip_bf16.h>
#include <cmath>

#define BB 4
#define NN 2048
#define DIN 128
#define HH 4
#define HD 32
#define KSEL 204            // int(0.1 * 2048)
#define BH (BB*HH)
#define KPAD 256            // K padded to 8 MFMA steps of 32
#define KST 264             // LDS row stride (bf16 elems): 132 words, mod32=4 -> 2-way (free)

typedef __attribute__((ext_vector_type(8))) short short8;
typedef __attribute__((ext_vector_type(4))) float float4v;

static __device__ inline short f2bf(float x) {
    __hip_bfloat16 b = __float2bfloat16(x);   // RNE
    return __builtin_bit_cast(short, b);
}

// ---------------------------------------------------------------------------
// K0: wa[half][h][f] = sum_d W[h][f][d] * a[h][half*32 + d]   (f32 exact path for s)
__global__ __launch_bounds__(256) void wa_kernel(const float* __restrict__ W,
                                                 const float* __restrict__ a,
                                                 float* __restrict__ wa) {
    int t = blockIdx.x * 256 + threadIdx.x;   // 0..1023
    int half = t >> 9, rem = t & 511, hh = rem >> 7, f = rem & 127;
    const float* Wp = W + (size_t)hh * (DIN * HD) + f * HD;
    const float* ap = a + hh * 64 + half * 32;
    float acc = 0.f;
#pragma unroll
    for (int d = 0; d < 32; ++d) acc += Wp[d] * ap[d];
    wa[half * 512 + hh * 128 + f] = acc;
}

// ---------------------------------------------------------------------------
// K1: Whg[bh][n][d] (bf16) = h[b][n][:] @ W[h][:][d]  via MFMA 16x16x32 bf16
__global__ __launch_bounds__(256) void wh_kernel(const float* __restrict__ h,
                                                 const float* __restrict__ W,
                                                 short* __restrict__ Whg) {
    int bh = blockIdx.x >> 4, rtile = blockIdx.x & 15;
    int b = bh >> 2, hh = bh & 3;
    __shared__ short WT[32][136];   // WT[n][k] = bf16(W[hh][k][n]); stride 136 avoids conflicts
    int t = threadIdx.x;
    for (int e = t; e < 32 * 128; e += 256) {
        int n = e >> 7, k = e & 127;
        WT[n][k] = f2bf(W[(size_t)hh * (DIN * HD) + k * HD + n]);
    }
    __syncthreads();
    int w = t >> 6, lane = t & 63, mr = lane & 15, quad = lane >> 4;
    int row_base = rtile * 128;
#pragma unroll
    for (int q = 0; q < 4; ++q) {
        int tt = w * 4 + q;
        int rt = tt >> 1, ct = tt & 1;
        int row0 = row_base + rt * 16;
        const float* hrow = h + ((size_t)b * NN + row0 + mr) * DIN + quad * 8;
        float4v acc = {0.f, 0.f, 0.f, 0.f};
#pragma unroll
        for (int ks = 0; ks < 4; ++ks) {
            const float* hp = hrow + ks * 32;
            float4 x0 = *(const float4*)hp;
            float4 x1 = *(const float4*)(hp + 4);
            short8 afr;
            afr[0] = f2bf(x0.x); afr[1] = f2bf(x0.y); afr[2] = f2bf(x0.z); afr[3] = f2bf(x0.w);
            afr[4] = f2bf(x1.x); afr[5] = f2bf(x1.y); afr[6] = f2bf(x1.z); afr[7] = f2bf(x1.w);
            short8 bfr = *(const short8*)&WT[ct * 16 + mr][ks * 32 + quad * 8];
            acc = __builtin_amdgcn_mfma_f32_16x16x32_bf16(afr, bfr, acc, 0, 0, 0);
        }
#pragma unroll
        for (int r = 0; r < 4; ++r) {
            int rowg = row0 + quad * 4 + r;
            Whg[((size_t)bh * NN + rowg) * HD + ct * 16 + mr] = f2bf(acc[r]);
        }
    }
}

// ---------------------------------------------------------------------------
// K2: s_i = h . wa1[h],  s_j = h . wa2[h]  (f32 exact; feeds top-k). Also zeroes rank.
__global__ __launch_bounds__(256) void s_kernel(const float* __restrict__ h,
                                                const float* __restrict__ wa,
                                                float* __restrict__ si, float* __restrict__ sj,
                                                int* __restrict__ rank) {
    int bh = blockIdx.x >> 3, chunk = blockIdx.x & 7;
    int b = bh >> 2, hh = bh & 3;
    __shared__ float w1[128], w2[128];
    int t = threadIdx.x;
    if (t < 128) w1[t] = wa[hh * 128 + t];
    else w2[t - 128] = wa[512 + hh * 128 + (t - 128)];
    __syncthreads();
    int n = chunk * 256 + t;
    const float4* hr = (const float4*)(h + ((size_t)b * NN + n) * DIN);
    float s1 = 0.f, s2 = 0.f;
#pragma unroll 8
    for (int q = 0; q < 32; ++q) {
        float4 x = hr[q];
        s1 += x.x * w1[q*4] + x.y * w1[q*4+1] + x.z * w1[q*4+2] + x.w * w1[q*4+3];
        s2 += x.x * w2[q*4] + x.y * w2[q*4+1] + x.z * w2[q*4+2] + x.w * w2[q*4+3];
    }
    int o = bh * NN + n;
    si[o] = s1; sj[o] = s2; rank[o] = 0;
}

// ---------------------------------------------------------------------------
// K3: partial rank counts. grid = BH*16; block handles 128 jp's vs all 2048 j's.
__global__ __launch_bounds__(256) void rankp_kernel(const float* __restrict__ sj,
                                                    int* __restrict__ rank) {
    int bh = blockIdx.x >> 4, jpc = blockIdx.x & 15;
    __shared__ float sv[128];
    int t = threadIdx.x;
    if (t < 128) sv[t] = sj[bh * NN + jpc * 128 + t];
    __syncthreads();
    int j0 = t * 8;
    const float* sjb = sj + bh * NN;
    float v[8]; int cnt[8];
#pragma unroll
    for (int r = 0; r < 8; ++r) { v[r] = sjb[j0 + r]; cnt[r] = 0; }
    int jpbase = jpc * 128;
    for (int jp = 0; jp < 128; ++jp) {
        float x = sv[jp];
        int jg = jpbase + jp;
#pragma unroll
        for (int r = 0; r < 8; ++r)
            cnt[r] += (x > v[r]) ? 1 : ((x == v[r] && jg < j0 + r) ? 1 : 0);
    }
#pragma unroll
    for (int r = 0; r < 8; ++r) atomicAdd(&rank[bh * NN + j0 + r], cnt[r]);
}

// ---------------------------------------------------------------------------
// K4: compact selected (rank < KSEL) ascending; sjsel + global max. Shuffle scan.
__global__ __launch_bounds__(256) void compact_kernel(const float* __restrict__ sj,
                                                      const int* __restrict__ rank,
                                                      int* __restrict__ idxsel,
                                                      float* __restrict__ sjsel,
                                                      float* __restrict__ sjmax) {
    int bh = blockIdx.x;
    int t = threadIdx.x, lane = t & 63, w = t >> 6;
    const int base = bh * NN;
    int flags[8], cnt = 0;
    float lmax = -1e30f;
    int j0 = t * 8;
#pragma unroll
    for (int r = 0; r < 8; ++r) {
        int j = j0 + r;
        int f = (rank[base + j] < KSEL) ? 1 : 0;
        flags[r] = f; cnt += f;
        lmax = fmaxf(lmax, sj[base + j]);
    }
    int sc = cnt;
#pragma unroll
    for (int off = 1; off < 64; off <<= 1) {
        int u = __shfl_up(sc, off);
        if (lane >= off) sc += u;
    }
    float mx = lmax;
#pragma unroll
    for (int off = 32; off >= 1; off >>= 1) mx = fmaxf(mx, __shfl_xor(mx, off));
    __shared__ int wtot[4], woff[4];
    __shared__ float wmax[4];
    if (lane == 63) wtot[w] = sc;
    if (lane == 0) wmax[w] = mx;
    __syncthreads();
    if (t == 0) {
        int run = 0;
        for (int i = 0; i < 4; ++i) { woff[i] = run; run += wtot[i]; }
        sjmax[bh] = fmaxf(fmaxf(wmax[0], wmax[1]), fmaxf(wmax[2], wmax[3]));
    }
    __syncthreads();
    int pos = woff[w] + sc - cnt;
#pragma unroll
    for (int r = 0; r < 8; ++r) {
        if (flags[r]) {
            int j = j0 + r;
            idxsel[bh * KSEL + pos] = j;
            sjsel[bh * KSEL + pos] = sj[base + j];
            pos++;
        }
    }
}

// ---------------------------------------------------------------------------
// K5: main attention. Block = (bh, 32 rows). Phase1: coef+Z (f32). Phase2: MFMA P@Wh.
__global__ __launch_bounds__(256) void attn_kernel(
        const float* __restrict__ adj, const short* __restrict__ Whg,
        const float* __restrict__ si, const int* __restrict__ idxsel,
        const float* __restrict__ sjsel, const float* __restrict__ sjmax,
        float* __restrict__ out) {
    int bh = blockIdx.x >> 6, tile = blockIdx.x & 63;
    int b = bh >> 2, hh = bh & 3;
    __shared__ short PS[32][KST];    // P[i][jj] bf16 (coef = exp * adj)
    __shared__ short WhB[32][KST];   // WhB[d][jj] = bf16 Wh[sel jj][d]  (B-operand layout)
    __shared__ int   idxS[KSEL];
    __shared__ float sjS[KSEL];
    __shared__ float invZ[32];
    int t = threadIdx.x;
    for (int j = t; j < KSEL; j += 256) {
        idxS[j] = idxsel[bh * KSEL + j];
        sjS[j]  = sjsel[bh * KSEL + j];
    }
    __syncthreads();
    // stage Wh (bf16, transposed) for selected neighbors
    for (int e = t; e < KSEL * HD; e += 256) {
        int j = e >> 5, d = e & 31;
        WhB[d][j] = Whg[((size_t)bh * NN + idxS[j]) * HD + d];
    }
    // zero K-tail [KSEL, KPAD)
    for (int e = t; e < 32 * (KPAD - KSEL); e += 256) {
        int r = e / (KPAD - KSEL), c = KSEL + e % (KPAD - KSEL);
        PS[r][c] = 0; WhB[r][c] = 0;
    }
    float smax = sjmax[bh];
    int w = t >> 6, lane = t & 63;
    const float* adjb = adj + (size_t)b * NN * NN;
    // Phase 1: coefficients + softmax denominators (f32 exact)
#pragma unroll
    for (int rr = 0; rr < 8; ++rr) {
        int i_loc = w * 8 + rr;
        int i = tile * 32 + i_loc;
        float siv = si[bh * NN + i];
        float m = siv + smax;
        m = (m >= 0.f) ? m : 0.2f * m;
        const float* adjrow = adjb + (size_t)i * NN;
        float z = 0.f;
        for (int jj = lane; jj < KSEL; jj += 64) {
            float e = siv + sjS[jj];
            e = (e >= 0.f) ? e : 0.2f * e;
            float c = __expf(e - m);
            z += c;
            PS[i_loc][jj] = f2bf(c * adjrow[idxS[jj]]);
        }
#pragma unroll
        for (int off = 32; off >= 1; off >>= 1) z += __shfl_xor(z, off);
        if (lane == 0) invZ[i_loc] = 1.0f / z;
    }
    __syncthreads();
    // Phase 2: 4 waves -> 4 disjoint 16x16 tiles of the 32x32 output
    int mi = w >> 1, ni = w & 1;
    int mr = lane & 15, quad = lane >> 4;
    const short* pA = &PS[mi * 16 + mr][quad * 8];
    const short* pB = &WhB[ni * 16 + mr][quad * 8];
    float4v acc = {0.f, 0.f, 0.f, 0.f};
#pragma unroll
    for (int ks = 0; ks < 8; ++ks) {
        short8 afr = *(const short8*)(pA + ks * 32);
        short8 bfr = *(const short8*)(pB + ks * 32);
        acc = __builtin_amdgcn_mfma_f32_16x16x32_bf16(afr, bfr, acc, 0, 0, 0);
    }
#pragma unroll
    for (int r = 0; r < 4; ++r) {
        int i_loc = mi * 16 + quad * 4 + r;
        int d = ni * 16 + mr;
        int rowg = tile * 32 + i_loc;
        out[((size_t)(b * NN + rowg)) * (HH * HD) + hh * HD + d] = acc[r] * invZ[i_loc];
    }
}

// ---------------------------------------------------------------------------
extern "C" void kernel_launch(void* const* d_in, const int* in_sizes, int n_in,
                              void* d_out, int out_size, void* d_ws, size_t ws_size,
                              hipStream_t stream) {
    const float* h   = (const float*)d_in[0];   // [B,N,DIN]
    const float* adj = (const float*)d_in[1];   // [B,N,N]
    const float* W   = (const float*)d_in[2];   // [H,DIN,HD]
    const float* a   = (const float*)d_in[3];   // [H,2*HD]
    float* out = (float*)d_out;                 // [B,N,H*HD]

    float* si     = (float*)d_ws;                    // BH*NN
    float* sj     = si + (size_t)BH * NN;            // BH*NN
    float* wa     = sj + (size_t)BH * NN;            // 1024
    float* sjmax  = wa + 1024;                       // BH
    float* sjsel  = sjmax + BH;                      // BH*KSEL
    int*   idxsel = (int*)(sjsel + (size_t)BH * KSEL);   // BH*KSEL
    int*   rank   = idxsel + (size_t)BH * KSEL;          // BH*NN
    short* Whg    = (short*)(rank + (size_t)BH * NN);    // BH*NN*HD bf16

    wa_kernel<<<4, 256, 0, stream>>>(W, a, wa);
    wh_kernel<<<BH * 16, 256, 0, stream>>>(h, W, Whg);
    s_kernel<<<BH * 8, 256, 0, stream>>>(h, wa, si, sj, rank);
    rankp_kernel<<<BH * 16, 256, 0, stream>>>(sj, rank);
    compact_kernel<<<BH, 256, 0, stream>>>(sj, rank, idxsel, sjsel, sjmax);
    attn_kernel<<<BH * 64, 256, 0, stream>>>(adj, Whg, si, idxsel, sjsel, sjmax, out);
}